// Round 13
// baseline (43.671 us; speedup 1.0000x reference)
//
#include <hip/hip_runtime.h>
#include <math.h>

// StructLoss: sqrt(mean(|grads4(outputs - labels)|) + 1e-16)
// grads4 linear -> compute on d = outputs - labels.
// [B=16, C=6, H=512, W=512] fp32; mean over B*4C*H*W.
//
// R12 structure (best, 38.0 us) + FENCE-FREE fused tail. Main loop
// unchanged: 768 blocks (3/CU), each owns a 64-row band; 18-slot LDS row
// ring of d; per strip stage only the 16 new rows (halo carries over,
// traffic 1.031x). Tail: partials published via RELAXED agent-scope
// atomicExch (data rides in the atomic -> no release fence / no
// buffer_wbl2, which caused R11's +23us L2 thrash); completion forced by
// consuming the exch return; RELAXED agent-scope counter fetch_add; last
// block reads partials with RELAXED agent-scope atomic loads and does a
// fixed-order double reduction (deterministic).

#define NTHREADS 256
#define TROWS 16
#define SLOTS 18
#define WV 512
#define HT 512
#define PLANES 96
#define SPB 4                                     // strips per block
#define BAND (SPB * TROWS)                        // 64 rows per block
#define BLOCKS_PER_PLANE (HT / BAND)              // 8
#define NBLOCKS (PLANES * BLOCKS_PER_PLANE)       // 768 = 3 blocks/CU
#define LDK_PRO 9                                 // 18 rows: float4/thread
#define LDK 8                                     // 16 rows: float4/thread

struct Row { float d[8]; float eL, eR; };

__device__ __forceinline__ Row lds_row(const float* __restrict__ sd,
                                       int slot, int lane) {
    Row row;
    const float4 a = *reinterpret_cast<const float4*>(sd + slot * WV + lane * 8);
    const float4 b = *reinterpret_cast<const float4*>(sd + slot * WV + lane * 8 + 4);
    row.d[0] = a.x; row.d[1] = a.y; row.d[2] = a.z; row.d[3] = a.w;
    row.d[4] = b.x; row.d[5] = b.y; row.d[6] = b.z; row.d[7] = b.w;
    const float up = __shfl_up(row.d[7], 1, 64);
    const float dn = __shfl_down(row.d[0], 1, 64);
    row.eL = (lane == 0)  ? 0.f : up;   // col 8l-1 (image zero-pad)
    row.eR = (lane == 63) ? 0.f : dn;   // col 8l+8 (image zero-pad)
    return row;
}

__device__ __forceinline__ float stencil(const Row& rp, const Row& rc,
                                         const Row& rn) {
    float a = 0.f;
    #pragma unroll
    for (int k = 0; k < 8; ++k) {
        const float cL = (k > 0) ? rc.d[k - 1] : rc.eL;
        const float cR = (k < 7) ? rc.d[k + 1] : rc.eR;
        const float pL = (k > 0) ? rp.d[k - 1] : rp.eL;
        const float pR = (k < 7) ? rp.d[k + 1] : rp.eR;
        const float nL = (k > 0) ? rn.d[k - 1] : rn.eL;
        const float nR = (k < 7) ? rn.d[k + 1] : rn.eR;

        const float gy = rp.d[k] - rn.d[k];   // x[i-1,j]   - x[i+1,j]
        const float gx = cL - cR;             // x[i,j-1]   - x[i,j+1]
        const float gD = pL - nR;             // x[i-1,j-1] - x[i+1,j+1]
        const float gd = pR - nL;             // x[i-1,j+1] - x[i+1,j-1]
        a += fabsf(gy) + fabsf(gx) + fabsf(gD) + fabsf(gd);
    }
    return a;
}

__global__ __launch_bounds__(NTHREADS) void struct_loss(
        const float* __restrict__ out_p, const float* __restrict__ lab_p,
        float* __restrict__ partials, unsigned* __restrict__ counter,
        float* __restrict__ out, double inv_count) {
    __shared__ float sd[SLOTS * WV];              // 36,864 B

    const int tid  = threadIdx.x;
    const int wid  = tid >> 6;
    const int lane = tid & 63;
    const int plane = blockIdx.x >> 3;            // / BLOCKS_PER_PLANE
    const int S0    = (blockIdx.x & (BLOCKS_PER_PLANE - 1)) * BAND;
    const int sbase = S0 % SLOTS;                 // slot of row S0-1
    const size_t pbase = (size_t)plane * (HT * WV);

    // ---- prologue: stage rows S0-1 .. S0+16 into slots (sbase+r)%18 ----
    {
        float4 ov[LDK_PRO], lv[LDK_PRO];
        #pragma unroll
        for (int k = 0; k < LDK_PRO; ++k) {
            const int p  = tid + NTHREADS * k;    // 0..2303
            const int r  = p >> 7;                // 0..17
            const int c4 = p & 127;
            const int g  = S0 - 1 + r;
            const int gc = max(g, 0);             // g <= 464 always
            const size_t goff = pbase + (size_t)gc * WV + c4 * 4;
            ov[k] = *reinterpret_cast<const float4*>(out_p + goff);
            lv[k] = *reinterpret_cast<const float4*>(lab_p + goff);
        }
        #pragma unroll
        for (int k = 0; k < LDK_PRO; ++k) {
            const int p  = tid + NTHREADS * k;
            const int r  = p >> 7;
            const int c4 = p & 127;
            const int g  = S0 - 1 + r;
            const float m = (g >= 0) ? 1.f : 0.f;
            int slot = sbase + r; if (slot >= SLOTS) slot -= SLOTS;
            float4 d;
            d.x = m * (ov[k].x - lv[k].x);
            d.y = m * (ov[k].y - lv[k].y);
            d.z = m * (ov[k].z - lv[k].z);
            d.w = m * (ov[k].w - lv[k].w);
            *reinterpret_cast<float4*>(sd + slot * WV + c4 * 4) = d;
        }
    }
    __syncthreads();

    float acc = 0.f;
    float4 ov[LDK], lv[LDK];

    #pragma unroll
    for (int t = 0; t < SPB; ++t) {
        const int R0 = S0 + t * TROWS;

        // Issue next strip's 16 NEW rows (R0+17 .. R0+32) before compute.
        if (t + 1 < SPB) {
            #pragma unroll
            for (int k = 0; k < LDK; ++k) {
                const int p  = tid + NTHREADS * k;   // 0..2047
                const int r  = p >> 7;               // 0..15
                const int c4 = p & 127;
                const int g  = R0 + 17 + r;
                const int gc = min(g, HT - 1);       // clamp: addr always valid
                const size_t goff = pbase + (size_t)gc * WV + c4 * 4;
                ov[k] = *reinterpret_cast<const float4*>(out_p + goff);
                lv[k] = *reinterpret_cast<const float4*>(lab_p + goff);
            }
            __builtin_amdgcn_sched_barrier(0);
        }

        // Compute strip rows R0+4*wid .. +3 (slots (sbase+16t+4wid+i)%18).
        {
            const int m0 = (sbase + 16 * t + 4 * wid) % SLOTS;
            int s_c = m0 + 1; if (s_c >= SLOTS) s_c -= SLOTS;
            Row rp = lds_row(sd, m0, lane);
            Row rc = lds_row(sd, s_c, lane);
            #pragma unroll
            for (int rr = 0; rr < 4; ++rr) {
                int s_n = m0 + 2 + rr; if (s_n >= SLOTS) s_n -= SLOTS;
                Row rn = lds_row(sd, s_n, lane);
                acc += stencil(rp, rc, rn);
                rp = rc;
                rc = rn;
            }
        }
        __syncthreads();                             // all reads done

        // Retire oldest 16 slots with the new rows.
        if (t + 1 < SPB) {
            #pragma unroll
            for (int k = 0; k < LDK; ++k) {
                const int p  = tid + NTHREADS * k;
                const int r  = p >> 7;
                const int c4 = p & 127;
                const int g  = R0 + 17 + r;
                const float m = (g < HT) ? 1.f : 0.f;  // zero-pad bottom
                int slot = (sbase + 16 * t + r) % SLOTS;
                float4 d;
                d.x = m * (ov[k].x - lv[k].x);
                d.y = m * (ov[k].y - lv[k].y);
                d.z = m * (ov[k].z - lv[k].z);
                d.w = m * (ov[k].w - lv[k].w);
                *reinterpret_cast<float4*>(sd + slot * WV + c4 * 4) = d;
            }
            __syncthreads();                         // writes visible
        }
    }

    // ---- wave + block reduction ----
    #pragma unroll
    for (int off = 32; off > 0; off >>= 1)
        acc += __shfl_down(acc, off, 64);

    __shared__ float smem[NTHREADS / 64];
    if (lane == 0) smem[wid] = acc;
    __syncthreads();

    // ---- fence-free publish + last-block detection ----
    __shared__ bool amLast;
    if (tid == 0) {
        float s = 0.f;
        #pragma unroll
        for (int w = 0; w < NTHREADS / 64; ++w) s += smem[w];
        // Publish via agent-scope atomic: data is IN the atomic, performed
        // at the coherent point -> no release fence / no buffer_wbl2.
        float old = __hip_atomic_exchange(&partials[blockIdx.x], s,
                                          __ATOMIC_RELAXED,
                                          __HIP_MEMORY_SCOPE_AGENT);
        asm volatile("" :: "v"(old));   // force vmcnt wait: exch complete
        const unsigned prev = __hip_atomic_fetch_add(counter, 1u,
                                                     __ATOMIC_RELAXED,
                                                     __HIP_MEMORY_SCOPE_AGENT);
        amLast = (prev == (unsigned)(NBLOCKS - 1));
    }
    __syncthreads();

    if (amLast) {
        // All 768 exchanges completed at the coherent point (each preceded
        // its block's counter add). Read back with agent-scope atomic loads
        // (bypass stale L1/L2). Fixed order -> deterministic.
        double s = 0.0;
        for (int i = tid; i < NBLOCKS; i += NTHREADS)
            s += (double)__hip_atomic_load(&partials[i], __ATOMIC_RELAXED,
                                           __HIP_MEMORY_SCOPE_AGENT);
        #pragma unroll
        for (int off = 32; off > 0; off >>= 1)
            s += __shfl_down(s, off, 64);
        __shared__ double dsm[NTHREADS / 64];
        if (lane == 0) dsm[wid] = s;
        __syncthreads();
        if (tid == 0) {
            double t = 0.0;
            #pragma unroll
            for (int w = 0; w < NTHREADS / 64; ++w) t += dsm[w];
            out[0] = (float)sqrt(t * inv_count + 1e-16);
        }
    }
}

extern "C" void kernel_launch(void* const* d_in, const int* in_sizes, int n_in,
                              void* d_out, int out_size, void* d_ws, size_t ws_size,
                              hipStream_t stream) {
    const float* outputs = (const float*)d_in[0];
    const float* labels  = (const float*)d_in[1];
    float* out = (float*)d_out;

    unsigned* counter = (unsigned*)d_ws;            // u32 at offset 0
    float* partials   = (float*)d_ws + 16;          // 768 floats at 64 B offset

    const double inv_count = 1.0 / (16.0 * 24.0 * 512.0 * 512.0);

    hipMemsetAsync(counter, 0, sizeof(unsigned), stream);
    struct_loss<<<NBLOCKS, NTHREADS, 0, stream>>>(outputs, labels, partials,
                                                  counter, out, inv_count);
}

// Round 14
// 38.841 us; speedup vs baseline: 1.1243x; 1.1243x over previous
//
#include <hip/hip_runtime.h>
#include <math.h>

// StructLoss: sqrt(mean(|grads4(outputs - labels)|) + 1e-16)
// grads4 linear -> compute on d = outputs - labels.
// [B=16, C=6, H=512, W=512] fp32; mean over B*4C*H*W.
//
// FINAL (= R12, best: 38.0 us, ~6.3 TB/s effective = measured streaming
// ceiling). Block owns a 64-row band (4 strips x 16 rows) of one plane;
// LDS is an 18-slot row ring (slot(g) = (g+1) mod 18) holding
// d = out - lab. Prologue stages 18 rows; each later strip stages only
// the 16 NEW rows (2 halo rows carry over) -> traffic 1.031x compulsory.
// Loads issued before compute, ds_writes after the read barrier (write
// set == slots being retired). Separate tiny final kernel: both fused-tail
// variants regressed (R11 fenced: +23us L2 thrash from buffer_wbl2;
// R13 fence-free agent-atomics: +5.7us) -> the second launch is the
// cheapest cross-XCD coherence point.

#define NTHREADS 256
#define TROWS 16
#define SLOTS 18
#define WV 512
#define HT 512
#define PLANES 96
#define SPB 4                                     // strips per block
#define BAND (SPB * TROWS)                        // 64 rows per block
#define BLOCKS_PER_PLANE (HT / BAND)              // 8
#define NBLOCKS (PLANES * BLOCKS_PER_PLANE)       // 768 = 3 blocks/CU
#define LDK_PRO 9                                 // 18 rows: float4/thread
#define LDK 8                                     // 16 rows: float4/thread

struct Row { float d[8]; float eL, eR; };

__device__ __forceinline__ Row lds_row(const float* __restrict__ sd,
                                       int slot, int lane) {
    Row row;
    const float4 a = *reinterpret_cast<const float4*>(sd + slot * WV + lane * 8);
    const float4 b = *reinterpret_cast<const float4*>(sd + slot * WV + lane * 8 + 4);
    row.d[0] = a.x; row.d[1] = a.y; row.d[2] = a.z; row.d[3] = a.w;
    row.d[4] = b.x; row.d[5] = b.y; row.d[6] = b.z; row.d[7] = b.w;
    const float up = __shfl_up(row.d[7], 1, 64);
    const float dn = __shfl_down(row.d[0], 1, 64);
    row.eL = (lane == 0)  ? 0.f : up;   // col 8l-1 (image zero-pad)
    row.eR = (lane == 63) ? 0.f : dn;   // col 8l+8 (image zero-pad)
    return row;
}

__device__ __forceinline__ float stencil(const Row& rp, const Row& rc,
                                         const Row& rn) {
    float a = 0.f;
    #pragma unroll
    for (int k = 0; k < 8; ++k) {
        const float cL = (k > 0) ? rc.d[k - 1] : rc.eL;
        const float cR = (k < 7) ? rc.d[k + 1] : rc.eR;
        const float pL = (k > 0) ? rp.d[k - 1] : rp.eL;
        const float pR = (k < 7) ? rp.d[k + 1] : rp.eR;
        const float nL = (k > 0) ? rn.d[k - 1] : rn.eL;
        const float nR = (k < 7) ? rn.d[k + 1] : rn.eR;

        const float gy = rp.d[k] - rn.d[k];   // x[i-1,j]   - x[i+1,j]
        const float gx = cL - cR;             // x[i,j-1]   - x[i,j+1]
        const float gD = pL - nR;             // x[i-1,j-1] - x[i+1,j+1]
        const float gd = pR - nL;             // x[i-1,j+1] - x[i+1,j-1]
        a += fabsf(gy) + fabsf(gx) + fabsf(gD) + fabsf(gd);
    }
    return a;
}

__global__ __launch_bounds__(NTHREADS) void struct_loss_partial(
        const float* __restrict__ out_p, const float* __restrict__ lab_p,
        float* __restrict__ partials) {
    __shared__ float sd[SLOTS * WV];              // 36,864 B

    const int tid  = threadIdx.x;
    const int wid  = tid >> 6;
    const int lane = tid & 63;
    const int plane = blockIdx.x >> 3;            // / BLOCKS_PER_PLANE
    const int S0    = (blockIdx.x & (BLOCKS_PER_PLANE - 1)) * BAND;
    const int sbase = S0 % SLOTS;                 // slot of row S0-1
    const size_t pbase = (size_t)plane * (HT * WV);

    // ---- prologue: stage rows S0-1 .. S0+16 into slots (sbase+r)%18 ----
    {
        float4 ov[LDK_PRO], lv[LDK_PRO];
        #pragma unroll
        for (int k = 0; k < LDK_PRO; ++k) {
            const int p  = tid + NTHREADS * k;    // 0..2303
            const int r  = p >> 7;                // 0..17
            const int c4 = p & 127;
            const int g  = S0 - 1 + r;
            const int gc = max(g, 0);             // g <= 464 always
            const size_t goff = pbase + (size_t)gc * WV + c4 * 4;
            ov[k] = *reinterpret_cast<const float4*>(out_p + goff);
            lv[k] = *reinterpret_cast<const float4*>(lab_p + goff);
        }
        #pragma unroll
        for (int k = 0; k < LDK_PRO; ++k) {
            const int p  = tid + NTHREADS * k;
            const int r  = p >> 7;
            const int c4 = p & 127;
            const int g  = S0 - 1 + r;
            const float m = (g >= 0) ? 1.f : 0.f;
            int slot = sbase + r; if (slot >= SLOTS) slot -= SLOTS;
            float4 d;
            d.x = m * (ov[k].x - lv[k].x);
            d.y = m * (ov[k].y - lv[k].y);
            d.z = m * (ov[k].z - lv[k].z);
            d.w = m * (ov[k].w - lv[k].w);
            *reinterpret_cast<float4*>(sd + slot * WV + c4 * 4) = d;
        }
    }
    __syncthreads();

    float acc = 0.f;
    float4 ov[LDK], lv[LDK];

    #pragma unroll
    for (int t = 0; t < SPB; ++t) {
        const int R0 = S0 + t * TROWS;

        // Issue next strip's 16 NEW rows (R0+17 .. R0+32) before compute.
        if (t + 1 < SPB) {
            #pragma unroll
            for (int k = 0; k < LDK; ++k) {
                const int p  = tid + NTHREADS * k;   // 0..2047
                const int r  = p >> 7;               // 0..15
                const int c4 = p & 127;
                const int g  = R0 + 17 + r;
                const int gc = min(g, HT - 1);       // clamp: addr always valid
                const size_t goff = pbase + (size_t)gc * WV + c4 * 4;
                ov[k] = *reinterpret_cast<const float4*>(out_p + goff);
                lv[k] = *reinterpret_cast<const float4*>(lab_p + goff);
            }
            __builtin_amdgcn_sched_barrier(0);
        }

        // Compute strip rows R0+4*wid .. +3 (slots (sbase+16t+4wid+i)%18).
        {
            const int m0 = (sbase + 16 * t + 4 * wid) % SLOTS;
            int s_c = m0 + 1; if (s_c >= SLOTS) s_c -= SLOTS;
            Row rp = lds_row(sd, m0, lane);
            Row rc = lds_row(sd, s_c, lane);
            #pragma unroll
            for (int rr = 0; rr < 4; ++rr) {
                int s_n = m0 + 2 + rr; if (s_n >= SLOTS) s_n -= SLOTS;
                Row rn = lds_row(sd, s_n, lane);
                acc += stencil(rp, rc, rn);
                rp = rc;
                rc = rn;
            }
        }
        __syncthreads();                             // all reads done

        // Retire oldest 16 slots with the new rows.
        if (t + 1 < SPB) {
            #pragma unroll
            for (int k = 0; k < LDK; ++k) {
                const int p  = tid + NTHREADS * k;
                const int r  = p >> 7;
                const int c4 = p & 127;
                const int g  = R0 + 17 + r;
                const float m = (g < HT) ? 1.f : 0.f;  // zero-pad bottom
                int slot = (sbase + 16 * t + r) % SLOTS;
                float4 d;
                d.x = m * (ov[k].x - lv[k].x);
                d.y = m * (ov[k].y - lv[k].y);
                d.z = m * (ov[k].z - lv[k].z);
                d.w = m * (ov[k].w - lv[k].w);
                *reinterpret_cast<float4*>(sd + slot * WV + c4 * 4) = d;
            }
            __syncthreads();                         // writes visible
        }
    }

    // ---- wave + block reduction ----
    #pragma unroll
    for (int off = 32; off > 0; off >>= 1)
        acc += __shfl_down(acc, off, 64);

    __shared__ float smem[NTHREADS / 64];
    if (lane == 0) smem[wid] = acc;
    __syncthreads();
    if (tid == 0) {
        float s = 0.f;
        #pragma unroll
        for (int w = 0; w < NTHREADS / 64; ++w) s += smem[w];
        partials[blockIdx.x] = s;
    }
}

__global__ __launch_bounds__(256) void struct_loss_final(
        const float* __restrict__ partial, float* __restrict__ out,
        int nparts, double inv_count) {
    double acc = 0.0;
    for (int i = threadIdx.x; i < nparts; i += blockDim.x)
        acc += (double)partial[i];
    #pragma unroll
    for (int off = 32; off > 0; off >>= 1)
        acc += __shfl_down(acc, off, 64);
    __shared__ double smem[4];
    const int lane = threadIdx.x & 63;
    const int wid  = threadIdx.x >> 6;
    if (lane == 0) smem[wid] = acc;
    __syncthreads();
    if (threadIdx.x == 0) {
        double s = smem[0] + smem[1] + smem[2] + smem[3];
        out[0] = (float)sqrt(s * inv_count + 1e-16);
    }
}

extern "C" void kernel_launch(void* const* d_in, const int* in_sizes, int n_in,
                              void* d_out, int out_size, void* d_ws, size_t ws_size,
                              hipStream_t stream) {
    const float* outputs = (const float*)d_in[0];
    const float* labels  = (const float*)d_in[1];
    float* out = (float*)d_out;
    float* partials = (float*)d_ws;   // NBLOCKS floats

    const double inv_count = 1.0 / (16.0 * 24.0 * 512.0 * 512.0);

    struct_loss_partial<<<NBLOCKS, NTHREADS, 0, stream>>>(outputs, labels, partials);
    struct_loss_final<<<1, 256, 0, stream>>>(partials, out, NBLOCKS, inv_count);
}